// Round 7
// baseline (123.564 us; speedup 1.0000x reference)
//
#include <hip/hip_runtime.h>
#include <hip/hip_bf16.h>

#define BB 16
#define TT 64
#define SS 256
#define DD 512

typedef __bf16 bf16x8 __attribute__((ext_vector_type(8)));
typedef float f32x4 __attribute__((ext_vector_type(4)));

__device__ __forceinline__ ushort f2b(float x) {
    __hip_bfloat16 h = __float2bfloat16(x);
    return __builtin_bit_cast(ushort, h);
}
__device__ __forceinline__ float b2f(ushort u) {
    unsigned int x = (unsigned int)u << 16;
    return __builtin_bit_cast(float, x);
}
// async 16B global -> LDS (linear dest: wave-uniform base + lane*16)
__device__ __forceinline__ void gload16(const ushort* g, ushort* l) {
    __builtin_amdgcn_global_load_lds(
        (const __attribute__((address_space(1))) unsigned int*)g,
        (__attribute__((address_space(3))) unsigned int*)l, 16, 0, 0);
}

// ---------------- fp32 -> bf16 cast of the 5 GEMM operands, one launch ----------
#define S_SRC (BB * TT * DD)   // 524288
#define S_MB  (BB * SS * DD)   // 2097152
#define S_WQ  (DD * DD)        // 262144
#define S_WC  (DD * DD)        // 262144
#define S_WO  (DD * 2 * DD)    // 524288

__global__ __launch_bounds__(256) void cast_all(
    const float* __restrict__ src, const float* __restrict__ mb,
    const float* __restrict__ wq, const float* __restrict__ wc,
    const float* __restrict__ wo,
    ushort* __restrict__ src_b, ushort* __restrict__ mb_b,
    ushort* __restrict__ wq_b, ushort* __restrict__ wc_b,
    ushort* __restrict__ wo_b) {
    int g = blockIdx.x * 256 + threadIdx.x;  // float4-group index
    const int G0 = S_SRC / 4, G1 = S_MB / 4, G2 = S_WQ / 4, G3 = S_WC / 4;
    const float* in;
    ushort* out;
    int local;
    if (g < G0) { in = src; out = src_b; local = g; }
    else if (g < G0 + G1) { in = mb; out = mb_b; local = g - G0; }
    else if (g < G0 + G1 + G2) { in = wq; out = wq_b; local = g - G0 - G1; }
    else if (g < G0 + G1 + G2 + G3) { in = wc; out = wc_b; local = g - G0 - G1 - G2; }
    else { in = wo; out = wo_b; local = g - G0 - G1 - G2 - G3; }
    float4 x = *(const float4*)(in + (size_t)local * 4);
    ushort4 y = {f2b(x.x), f2b(x.y), f2b(x.z), f2b(x.w)};
    *(ushort4*)(out + (size_t)local * 4) = y;
}

// ---------------- mega-GEMM: BK=128 (4 phases), single-buffer global_load_lds ---
// 64x64 tile, BK=128, K=512 -> 4 phases (half the barrier-drain events of BK=64).
// LDS 2 x 16 KB = 32 KB -> still 5 blocks/CU (20 waves/CU). Staging via
// global_load_lds width=16 into UNPADDED [64][128] bf16 tiles. Rule-21 both-sides
// XOR swizzle: stored[r][c] = data[r][c^(r&7)] via pre-swizzled per-lane global
// SOURCE + linear LDS dest; ds_read un-swizzles with chunk (kc*4+quad)^(l15&7).
// Bank distribution identical to the verified BK=64 scheme (8 lanes/bank-group).
// k-accumulation order (ascending 32-chunks) identical -> bit-identical output.
// Flat block id -> mode (1280 blocks, ~5/CU):
//   [0,128)    mode0: Ewq = exp(2*(src @ W_q^T + b_q))      fp32 (1024x512)
//   [128,256)  mode1: Y   = src @ Wo2^T + b_out             fp32 (1024x512)
//   [256,768)  mode2: Eu[b] = exp(2*(mb[b] @ W_c^T))        bf16 (256x512), batch 16
//   [768,1280) mode3: M2[b] = mb[b] @ Wo1^T                 bf16 (256x512), batch 16
__global__ __launch_bounds__(256) void mega_gemm(
    const ushort* __restrict__ src_b, const ushort* __restrict__ mb_b,
    const ushort* __restrict__ wq_b, const ushort* __restrict__ wc_b,
    const ushort* __restrict__ wo_b,
    const float* __restrict__ b_q, const float* __restrict__ b_out,
    float* __restrict__ Ewq, float* __restrict__ Y,
    ushort* __restrict__ Eu, ushort* __restrict__ M2) {
    __shared__ ushort Asm[64 * 128];   // 16 KB, linear (global_load_lds dest)
    __shared__ ushort Bsm[64 * 128];   // 16 KB
    const int id = blockIdx.x;
    const ushort* Ab;
    const ushort* Bb;
    const float* bias = nullptr;
    void* Cp;
    int ldb, N, m0, n0;
    bool exp2x, obf16, hasb;
    size_t coff = 0;
    if (id < 256) {
        const bool isY = id >= 128;
        const int l = id & 127;
        m0 = (l >> 3) * 64; n0 = (l & 7) * 64;
        Ab = src_b;
        Bb = isY ? (wo_b + DD) : wq_b;
        ldb = isY ? 2 * DD : DD;
        bias = isY ? b_out : b_q;
        hasb = true; exp2x = !isY; obf16 = false; N = DD;
        Cp = isY ? (void*)Y : (void*)Ewq;
    } else if (id < 768) {
        const int l = id - 256;
        const int bz = l >> 5, tl = l & 31;   // 4 (s) x 8 (d) tiles
        m0 = (tl >> 3) * 64; n0 = (tl & 7) * 64;
        Ab = mb_b + (size_t)bz * SS * DD;
        Bb = wc_b;
        ldb = DD;
        hasb = false; exp2x = true; obf16 = true; N = DD;
        Cp = (void*)Eu; coff = (size_t)bz * SS * DD;
    } else {
        const int l = id - 768;
        const int bz = l >> 5, tl = l & 31;   // 4 (s) x 8 (d) tiles
        m0 = (tl >> 3) * 64; n0 = (tl & 7) * 64;
        Ab = mb_b + (size_t)bz * SS * DD;
        Bb = wo_b;
        ldb = 2 * DD;
        hasb = false; exp2x = false; obf16 = true; N = DD;
        Cp = (void*)M2; coff = (size_t)bz * SS * DD;
    }

    const int tid = threadIdx.x;
    const int lane = tid & 63;
    const int wave = tid >> 6;
    const int wm = wave & 1, wn = wave >> 1;

    // staging: wave w stages rows [w*16,(w+1)*16) of A and B, 4 instrs each
    // (1 KB = 4 rows x 256 B per instr). lane -> (row=lane>>4 within 4, chunk=
    // lane&15 of 16); global source chunk pre-swizzled c^(lr&7).
    const int r4 = lane >> 4;       // 0..3 row-within-instr
    const int c16 = lane & 15;      // 0..15 chunk
    const ushort* Agj[4];
    const ushort* Bgj[4];
    ushort* Alj[4];
    ushort* Blj[4];
#pragma unroll
    for (int j = 0; j < 4; ++j) {
        const int lr = wave * 16 + j * 4 + r4;      // local row 0..63
        const int cs = c16 ^ (lr & 7);              // swizzled source chunk
        Agj[j] = Ab + (size_t)(m0 + lr) * DD + cs * 8;
        Bgj[j] = Bb + (size_t)(n0 + lr) * ldb + cs * 8;
        Alj[j] = &Asm[(wave * 16 + j * 4) * 128];   // wave-uniform dest
        Blj[j] = &Bsm[(wave * 16 + j * 4) * 128];
    }

    // fragment read addresses (ushort offsets), chunk un-swizzle on read side
    const int l15 = lane & 15, quad = lane >> 4;
    const int xr = l15 & 7;
    const int arow0 = (wm * 32 + l15) * 128, arow1 = arow0 + 16 * 128;
    const int brow0 = (wn * 32 + l15) * 128, brow1 = brow0 + 16 * 128;

    f32x4 acc00 = {0.f, 0.f, 0.f, 0.f}, acc01 = {0.f, 0.f, 0.f, 0.f};
    f32x4 acc10 = {0.f, 0.f, 0.f, 0.f}, acc11 = {0.f, 0.f, 0.f, 0.f};

    const int P = DD >> 7;  // 4 phases of BK=128
    for (int p = 0; p < P; ++p) {
        const int ko = p << 7;
        __syncthreads();  // prior phase's ds_reads complete before overwrite
#pragma unroll
        for (int j = 0; j < 4; ++j) {
            gload16(Agj[j] + ko, Alj[j]);
            gload16(Bgj[j] + ko, Blj[j]);
        }
        __syncthreads();  // drains vmcnt(0) -> tiles resident
#pragma unroll
        for (int kc = 0; kc < 4; ++kc) {
            const int c = ((kc * 4 + quad) ^ xr) * 8;
            bf16x8 fa0 = *(const bf16x8*)&Asm[arow0 + c];
            bf16x8 fa1 = *(const bf16x8*)&Asm[arow1 + c];
            bf16x8 fb0 = *(const bf16x8*)&Bsm[brow0 + c];
            bf16x8 fb1 = *(const bf16x8*)&Bsm[brow1 + c];
            acc00 = __builtin_amdgcn_mfma_f32_16x16x32_bf16(fa0, fb0, acc00, 0, 0, 0);
            acc01 = __builtin_amdgcn_mfma_f32_16x16x32_bf16(fa0, fb1, acc01, 0, 0, 0);
            acc10 = __builtin_amdgcn_mfma_f32_16x16x32_bf16(fa1, fb0, acc10, 0, 0, 0);
            acc11 = __builtin_amdgcn_mfma_f32_16x16x32_bf16(fa1, fb1, acc11, 0, 0, 0);
        }
    }
    // epilogue: C/D layout col=l15, row=quad*4+reg
    const int nA = n0 + wn * 32 + l15;
    float bias0 = 0.f, bias1 = 0.f;
    if (hasb) { bias0 = bias[nA]; bias1 = bias[nA + 16]; }
    float* Cf = (float*)Cp;
    ushort* Cb = (ushort*)Cp;
#pragma unroll
    for (int mt = 0; mt < 2; ++mt) {
        f32x4 accN0 = mt ? acc10 : acc00;
        f32x4 accN1 = mt ? acc11 : acc01;
#pragma unroll
        for (int r = 0; r < 4; ++r) {
            int m = m0 + wm * 32 + mt * 16 + quad * 4 + r;
            float v0 = accN0[r] + bias0;
            float v1 = accN1[r] + bias1;
            if (exp2x) { v0 = __expf(2.0f * v0); v1 = __expf(2.0f * v1); }
            size_t i0 = coff + (size_t)m * N + nA;
            if (obf16) { Cb[i0] = f2b(v0); Cb[i0 + 16] = f2b(v1); }
            else { Cf[i0] = v0; Cf[i0 + 16] = v1; }
        }
    }
}

// ---------------- fused align + sparsemax + output (R6-verbatim) ----------------
// Block = (2 t-rows, b). Mask-compacted score loop — only ACTIVE s rows
// (avg ~50%) get the 512-d loop. Sorted compaction via per-wave ballot ranks.
// Thread = (compact index ci = tid&127, d-half dh = tid>>7). Two d-terms share
// one reciprocal: va/d0 + vb/d1 = (va*d1 + vb*d0) * rcp(d0*d1).
__global__ __launch_bounds__(256) void align6(const float* __restrict__ Ewq,
                                              const ushort* __restrict__ Eu,
                                              const int* __restrict__ mask,
                                              const float* __restrict__ v,
                                              const ushort* __restrict__ M2,
                                              const float* __restrict__ Y,
                                              float* __restrict__ align_out,
                                              float* __restrict__ out0) {
    const int tg = blockIdx.x, b = blockIdx.y;
    const int t0 = tg * 2, t1 = t0 + 1;
    const int bt0 = b * TT + t0, bt1 = bt0 + 1;
    const int tid = threadIdx.x;
    const int lane = tid & 63;
    const int wave = tid >> 6;
    __shared__ float4 EL[DD];            // {E0, E1, v, 0} 8 KB
    __shared__ float pa[2][2][SS];       // partial a [dh][t][ci] 8 KB
    __shared__ float zc0[SS], zc1[SS];   // compact scores -> probs 2 KB
    __shared__ float pf0[SS], pf1[SS];   // full-row probs (zero-init) 2 KB
    __shared__ int lst[SS];              // sorted active s list 1 KB
    __shared__ int lstS0[SS], lstS1[SS]; // support lists 2 KB
    __shared__ float4 cmb[2][128];       // PV partial combine 4 KB
    __shared__ float svp[4];
    __shared__ int wcnt[4];
    __shared__ int cnt[2];

    if (tid < 2) cnt[tid] = 0;
    // ---- sorted mask compaction: ballot rank keeps lst ascending in s ----
    const int mk = mask[b * SS + tid];            // tid == s (SS == 256)
    const unsigned long long bal = __ballot(mk != 0);
    const int wr = __popcll(bal & ((1ull << lane) - 1ull));
    if (lane == 0) wcnt[wave] = __popcll(bal);
    // ---- EL preload + sum(v) (independent work before the sync) ----
    const float* E0p = Ewq + (size_t)bt0 * DD;
    const float* E1p = Ewq + (size_t)bt1 * DD;
    float pv = 0.f;
    for (int d = tid; d < DD; d += 256) {
        float vv = v[d];
        EL[d] = make_float4(E0p[d], E1p[d], vv, 0.f);
        pv += vv;
    }
    pf0[tid] = 0.f;
    pf1[tid] = 0.f;
#pragma unroll
    for (int off = 32; off > 0; off >>= 1) pv += __shfl_xor(pv, off, 64);
    if (lane == 0) svp[wave] = pv;
    __syncthreads();
    const float sv = svp[0] + svp[1] + svp[2] + svp[3];
    int base = 0;
    for (int w = 0; w < wave; ++w) base += wcnt[w];
    const int na = wcnt[0] + wcnt[1] + wcnt[2] + wcnt[3];
    if (mk) lst[base + wr] = tid;
    __syncthreads();

    if (na == 0) {  // pathological all-masked row: sparsemax of all-equal = uniform
        const float u = 1.0f / (float)SS;
        align_out[((size_t)t0 * BB + b) * SS + tid] = u;
        align_out[((size_t)t1 * BB + b) * SS + tid] = u;
        const int ch = tid & 127, sg = tid >> 7;
        if (sg == 0) {
            const ushort* M2b = M2 + (size_t)b * SS * DD + ch * 4;
            float4 at = {0.f, 0.f, 0.f, 0.f};
            for (int s = 0; s < SS; ++s) {
                ushort4 m4 = *(const ushort4*)(M2b + (size_t)s * DD);
                at.x += b2f(m4.x); at.y += b2f(m4.y);
                at.z += b2f(m4.z); at.w += b2f(m4.w);
            }
            const float4* Y0 = (const float4*)(Y + (size_t)bt0 * DD);
            const float4* Y1 = (const float4*)(Y + (size_t)bt1 * DD);
            float4 y0 = Y0[ch], y1 = Y1[ch];
            float4 o0 = {at.x * u + y0.x, at.y * u + y0.y, at.z * u + y0.z, at.w * u + y0.w};
            float4 o1 = {at.x * u + y1.x, at.y * u + y1.y, at.z * u + y1.z, at.w * u + y1.w};
            ((float4*)(out0 + ((size_t)t0 * BB + b) * DD))[ch] = o0;
            ((float4*)(out0 + ((size_t)t1 * BB + b) * DD))[ch] = o1;
        }
        return;
    }

    // ---- scores on active rows only; thread owns (ci, d-half) ----
    const int ci0 = tid & 127, dh = tid >> 7;
    const int dbase = dh * 256;
    for (int ci = ci0; ci < na; ci += 128) {
        const int s = lst[ci];
        const ushort* U = Eu + ((size_t)b * SS + s) * DD + dbase;
        float a0 = 0.f, a1 = 0.f;
#pragma unroll 4
        for (int dd = 0; dd < 256; dd += 8) {
            union { uint4 q; unsigned w[4]; } uw;
            uw.q = *(const uint4*)(U + dd);
#pragma unroll
            for (int jj = 0; jj < 4; ++jj) {
                const unsigned wd = uw.w[jj];
                const float ulo = __builtin_bit_cast(float, wd << 16);
                const float uhi = __builtin_bit_cast(float, wd & 0xffff0000u);
                const float4 eA = EL[dbase + dd + jj * 2];
                const float4 eB = EL[dbase + dd + jj * 2 + 1];
                const float d0 = __builtin_fmaf(eA.x, ulo, 1.0f);
                const float d1 = __builtin_fmaf(eB.x, uhi, 1.0f);
                float num = eA.z * d1;
                num = __builtin_fmaf(eB.z, d0, num);
                a0 = __builtin_fmaf(num, __builtin_amdgcn_rcpf(d0 * d1), a0);
                const float e0 = __builtin_fmaf(eA.y, ulo, 1.0f);
                const float e1 = __builtin_fmaf(eB.y, uhi, 1.0f);
                float nu1 = eA.z * e1;
                nu1 = __builtin_fmaf(eB.z, e0, nu1);
                a1 = __builtin_fmaf(nu1, __builtin_amdgcn_rcpf(e0 * e1), a1);
            }
        }
        pa[dh][0][ci] = a0;
        pa[dh][1][ci] = a1;
    }
    __syncthreads();
    for (int ci = tid; ci < na; ci += 256) {
        zc0[ci] = sv - 2.0f * (pa[0][0][ci] + pa[1][0][ci]);
        zc1[ci] = sv - 2.0f * (pa[0][1][ci] + pa[1][1][ci]);
    }
    __syncthreads();

    // ---- sparsemax over compact arrays (length na), waves 0/1 ----
    if (wave < 2) {
        float* zz = wave ? zc1 : zc0;
        float z0 = lane < na ? zz[lane] : -1e9f;
        float z1 = lane + 64 < na ? zz[lane + 64] : -1e9f;
        float z2 = lane + 128 < na ? zz[lane + 128] : -1e9f;
        float z3 = lane + 192 < na ? zz[lane + 192] : -1e9f;
        float mx = fmaxf(fmaxf(z0, z1), fmaxf(z2, z3));
#pragma unroll
        for (int off = 32; off > 0; off >>= 1) mx = fmaxf(mx, __shfl_xor(mx, off, 64));
        z0 -= mx; z1 -= mx; z2 -= mx; z3 -= mx;
        float lo = -1.0f, hi = 0.0f;
        for (int it = 0; it < 20; ++it) {
            float mid = 0.5f * (lo + hi);
            float ssum = fmaxf(z0 - mid, 0.f) + fmaxf(z1 - mid, 0.f) +
                         fmaxf(z2 - mid, 0.f) + fmaxf(z3 - mid, 0.f);
#pragma unroll
            for (int off = 32; off > 0; off >>= 1) ssum += __shfl_xor(ssum, off, 64);
            if (ssum >= 1.0f) lo = mid; else hi = mid;
        }
        float tau = 0.5f * (lo + hi);
        if (lane < na) zz[lane] = fmaxf(z0 - tau, 0.f);
        if (lane + 64 < na) zz[lane + 64] = fmaxf(z1 - tau, 0.f);
        if (lane + 128 < na) zz[lane + 128] = fmaxf(z2 - tau, 0.f);
        if (lane + 192 < na) zz[lane + 192] = fmaxf(z3 - tau, 0.f);
    }
    __syncthreads();

    // ---- scatter probs to full rows + build support lists ----
    for (int ci = tid; ci < na; ci += 256) {
        const int s = lst[ci];
        const float p0 = zc0[ci], p1 = zc1[ci];
        pf0[s] = p0;
        pf1[s] = p1;
        if (p0 > 0.f) lstS0[atomicAdd(&cnt[0], 1)] = s;
        if (p1 > 0.f) lstS1[atomicAdd(&cnt[1], 1)] = s;
    }
    __syncthreads();
    align_out[((size_t)t0 * BB + b) * SS + tid] = pf0[tid];
    align_out[((size_t)t1 * BB + b) * SS + tid] = pf1[tid];
    const int n0c = cnt[0], n1c = cnt[1];

    // ---- PV + Y: thread ch owns d=ch*4..+3 for BOTH t; sg splits list ----
    const int ch = tid & 127, sg = tid >> 7;
    const ushort* M2b = M2 + (size_t)b * SS * DD + ch * 4;
    float4 at0 = {0.f, 0.f, 0.f, 0.f}, at1 = {0.f, 0.f, 0.f, 0.f};
#pragma unroll 4
    for (int j = sg; j < n0c; j += 2) {
        int s = lstS0[j];
        float p = pf0[s];
        ushort4 m4 = *(const ushort4*)(M2b + (size_t)s * DD);
        at0.x = __builtin_fmaf(p, b2f(m4.x), at0.x);
        at0.y = __builtin_fmaf(p, b2f(m4.y), at0.y);
        at0.z = __builtin_fmaf(p, b2f(m4.z), at0.z);
        at0.w = __builtin_fmaf(p, b2f(m4.w), at0.w);
    }
#pragma unroll 4
    for (int j = sg; j < n1c; j += 2) {
        int s = lstS1[j];
        float p = pf1[s];
        ushort4 m4 = *(const ushort4*)(M2b + (size_t)s * DD);
        at1.x = __builtin_fmaf(p, b2f(m4.x), at1.x);
        at1.y = __builtin_fmaf(p, b2f(m4.y), at1.y);
        at1.z = __builtin_fmaf(p, b2f(m4.z), at1.z);
        at1.w = __builtin_fmaf(p, b2f(m4.w), at1.w);
    }
    if (sg == 1) { cmb[0][ch] = at0; cmb[1][ch] = at1; }
    __syncthreads();
    if (sg == 0) {
        float4 p0 = cmb[0][ch], p1 = cmb[1][ch];
        const float4* Y0 = (const float4*)(Y + (size_t)bt0 * DD);
        const float4* Y1 = (const float4*)(Y + (size_t)bt1 * DD);
        float4 y0 = Y0[ch], y1 = Y1[ch];
        float4 o0, o1;
        o0.x = at0.x + p0.x + y0.x; o0.y = at0.y + p0.y + y0.y;
        o0.z = at0.z + p0.z + y0.z; o0.w = at0.w + p0.w + y0.w;
        o1.x = at1.x + p1.x + y1.x; o1.y = at1.y + p1.y + y1.y;
        o1.z = at1.z + p1.z + y1.z; o1.w = at1.w + p1.w + y1.w;
        float4* O0 = (float4*)(out0 + ((size_t)t0 * BB + b) * DD);
        float4* O1 = (float4*)(out0 + ((size_t)t1 * BB + b) * DD);
        O0[ch] = o0;
        O1[ch] = o1;
    }
}

extern "C" void kernel_launch(void* const* d_in, const int* in_sizes, int n_in,
                              void* d_out, int out_size, void* d_ws, size_t ws_size,
                              hipStream_t stream) {
    const float* source = (const float*)d_in[0];       // (B,T,D)
    const float* memory_bank = (const float*)d_in[1];  // (B,S,D)
    const int* memory_mask = (const int*)d_in[2];      // (B,S)
    const float* W_q = (const float*)d_in[3];          // (D,D)
    const float* b_q = (const float*)d_in[4];          // (D,)
    const float* W_c = (const float*)d_in[5];          // (D,D)
    const float* v = (const float*)d_in[6];            // (D,)
    const float* W_out = (const float*)d_in[7];        // (D,2D)
    const float* b_out = (const float*)d_in[8];        // (D,)

    float* out0 = (float*)d_out;                   // attn_h (T,B,D)
    float* out1 = out0 + (size_t)TT * BB * DD;     // align_vectors (T,B,S)

    // workspace (~19.3 MB)
    float* Ewq = (float*)d_ws;                     // (B*T, D) fp32 exp(2wq)  2 MB
    float* Y = Ewq + S_SRC;                        // (B*T, D) fp32 src@Wo2^T+b 2 MB
    ushort* Eu = (ushort*)(Y + S_SRC);             // (B, S, D) bf16 exp(2uh) 4 MB
    ushort* M2 = Eu + S_MB;                        // (B, S, D) bf16 mb@Wo1^T 4 MB
    ushort* src_b = M2 + S_MB;                     // 1 MB
    ushort* mb_b = src_b + S_SRC;                  // 4 MB
    ushort* wqw_b = mb_b + S_MB;                   // 0.5 MB
    ushort* wcw_b = wqw_b + S_WQ;                  // 0.5 MB
    ushort* wo_b = wcw_b + S_WC;                   // 1 MB

    dim3 blk(256);
    // 1. cast bf16 operands
    int ngroups = (S_SRC + S_MB + S_WQ + S_WC + S_WO) / 4;
    cast_all<<<dim3(ngroups / 256), blk, 0, stream>>>(
        source, memory_bank, W_q, W_c, W_out, src_b, mb_b, wqw_b, wcw_b, wo_b);
    // 2. all four GEMMs, one dispatch (1280 blocks of 64x64 tiles, ~5/CU)
    mega_gemm<<<dim3(1280), blk, 0, stream>>>(
        src_b, mb_b, wqw_b, wcw_b, wo_b, b_q, b_out, Ewq, Y, Eu, M2);
    // 3. fused align + sparsemax + output (mask-compacted)
    align6<<<dim3(TT / 2, BB), blk, 0, stream>>>(
        Ewq, Eu, memory_mask, v, M2, Y, out1, out0);
}

// Round 9
// 120.796 us; speedup vs baseline: 1.0229x; 1.0229x over previous
//
#include <hip/hip_runtime.h>
#include <hip/hip_bf16.h>

#define BB 16
#define TT 64
#define SS 256
#define DD 512

typedef __bf16 bf16x8 __attribute__((ext_vector_type(8)));
typedef float f32x4 __attribute__((ext_vector_type(4)));

__device__ __forceinline__ ushort f2b(float x) {
    __hip_bfloat16 h = __float2bfloat16(x);
    return __builtin_bit_cast(ushort, h);
}
__device__ __forceinline__ float b2f(ushort u) {
    unsigned int x = (unsigned int)u << 16;
    return __builtin_bit_cast(float, x);
}
// async 16B global -> LDS (linear dest: wave-uniform base + lane*16)
__device__ __forceinline__ void gload16(const ushort* g, ushort* l) {
    __builtin_amdgcn_global_load_lds(
        (const __attribute__((address_space(1))) unsigned int*)g,
        (__attribute__((address_space(3))) unsigned int*)l, 16, 0, 0);
}

// ---------------- fp32 -> bf16 cast of the 5 GEMM operands, one launch ----------
#define S_SRC (BB * TT * DD)   // 524288
#define S_MB  (BB * SS * DD)   // 2097152
#define S_WQ  (DD * DD)        // 262144
#define S_WC  (DD * DD)        // 262144
#define S_WO  (DD * 2 * DD)    // 524288

__global__ __launch_bounds__(256) void cast_all(
    const float* __restrict__ src, const float* __restrict__ mb,
    const float* __restrict__ wq, const float* __restrict__ wc,
    const float* __restrict__ wo,
    ushort* __restrict__ src_b, ushort* __restrict__ mb_b,
    ushort* __restrict__ wq_b, ushort* __restrict__ wc_b,
    ushort* __restrict__ wo_b) {
    int g = blockIdx.x * 256 + threadIdx.x;  // float4-group index
    const int G0 = S_SRC / 4, G1 = S_MB / 4, G2 = S_WQ / 4, G3 = S_WC / 4;
    const float* in;
    ushort* out;
    int local;
    if (g < G0) { in = src; out = src_b; local = g; }
    else if (g < G0 + G1) { in = mb; out = mb_b; local = g - G0; }
    else if (g < G0 + G1 + G2) { in = wq; out = wq_b; local = g - G0 - G1; }
    else if (g < G0 + G1 + G2 + G3) { in = wc; out = wc_b; local = g - G0 - G1 - G2; }
    else { in = wo; out = wo_b; local = g - G0 - G1 - G2 - G3; }
    float4 x = *(const float4*)(in + (size_t)local * 4);
    ushort4 y = {f2b(x.x), f2b(x.y), f2b(x.z), f2b(x.w)};
    *(ushort4*)(out + (size_t)local * 4) = y;
}

// ---------------- mega-GEMM (R6-verbatim: single-buffer global_load_lds) -------
// 64x64 tile, BK=64, K=512 (8 phases). Staging via global_load_lds width=16 into
// an UNPADDED [64][64] bf16 tile. Bank conflicts fixed by rule-21 both-sides XOR
// swizzle: global SOURCE chunk pre-swizzled c^(r&7), LDS dest linear, ds_read
// uses chunk (kc*4+quad)^(l15&7) -> 2-way (free).
// Flat block id -> mode (1280 blocks, ~5/CU):
//   [0,128)    mode0: Ewq = exp(2*(src @ W_q^T + b_q))      fp32 (1024x512)
//   [128,256)  mode1: Y   = src @ Wo2^T + b_out             fp32 (1024x512)
//   [256,768)  mode2: Eu[b] = exp(2*(mb[b] @ W_c^T))        bf16 (256x512), batch 16
//   [768,1280) mode3: M2[b] = mb[b] @ Wo1^T                 bf16 (256x512), batch 16
__global__ __launch_bounds__(256) void mega_gemm(
    const ushort* __restrict__ src_b, const ushort* __restrict__ mb_b,
    const ushort* __restrict__ wq_b, const ushort* __restrict__ wc_b,
    const ushort* __restrict__ wo_b,
    const float* __restrict__ b_q, const float* __restrict__ b_out,
    float* __restrict__ Ewq, float* __restrict__ Y,
    ushort* __restrict__ Eu, ushort* __restrict__ M2) {
    __shared__ ushort Asm[64 * 64];   // 8 KB, linear (global_load_lds dest)
    __shared__ ushort Bsm[64 * 64];   // 8 KB
    const int id = blockIdx.x;
    const ushort* Ab;
    const ushort* Bb;
    const float* bias = nullptr;
    void* Cp;
    int ldb, N, m0, n0;
    bool exp2x, obf16, hasb;
    size_t coff = 0;
    if (id < 256) {
        const bool isY = id >= 128;
        const int l = id & 127;
        m0 = (l >> 3) * 64; n0 = (l & 7) * 64;
        Ab = src_b;
        Bb = isY ? (wo_b + DD) : wq_b;
        ldb = isY ? 2 * DD : DD;
        bias = isY ? b_out : b_q;
        hasb = true; exp2x = !isY; obf16 = false; N = DD;
        Cp = isY ? (void*)Y : (void*)Ewq;
    } else if (id < 768) {
        const int l = id - 256;
        const int bz = l >> 5, tl = l & 31;   // 4 (s) x 8 (d) tiles
        m0 = (tl >> 3) * 64; n0 = (tl & 7) * 64;
        Ab = mb_b + (size_t)bz * SS * DD;
        Bb = wc_b;
        ldb = DD;
        hasb = false; exp2x = true; obf16 = true; N = DD;
        Cp = (void*)Eu; coff = (size_t)bz * SS * DD;
    } else {
        const int l = id - 768;
        const int bz = l >> 5, tl = l & 31;   // 4 (s) x 8 (d) tiles
        m0 = (tl >> 3) * 64; n0 = (tl & 7) * 64;
        Ab = mb_b + (size_t)bz * SS * DD;
        Bb = wo_b;
        ldb = 2 * DD;
        hasb = false; exp2x = false; obf16 = true; N = DD;
        Cp = (void*)M2; coff = (size_t)bz * SS * DD;
    }

    const int tid = threadIdx.x;
    const int lane = tid & 63;
    const int wave = tid >> 6;
    const int wm = wave & 1, wn = wave >> 1;

    // staging: wave w stages A rows [w*16,(w+1)*16) and B rows likewise, 2 instrs
    // each (1 KB = 8 rows per instr). lane -> (row=lane>>3, chunk=lane&7); global
    // source chunk is XOR-swizzled so linear LDS holds stored[r][c]=data[r][c^(r&7)].
    const int rl = lane >> 3;           // 0..7 row-within-8
    const int csw = (lane & 7) ^ rl;    // swizzled source chunk
    const ushort* Ag0 = Ab + (size_t)(m0 + wave * 16 + rl) * DD + csw * 8;
    const ushort* Ag1 = Ag0 + (size_t)8 * DD;
    const ushort* Bg0 = Bb + (size_t)(n0 + wave * 16 + rl) * ldb + csw * 8;
    const ushort* Bg1 = Bg0 + (size_t)8 * ldb;
    ushort* Al0 = &Asm[(wave * 16) * 64];
    ushort* Al1 = &Asm[(wave * 16 + 8) * 64];
    ushort* Bl0 = &Bsm[(wave * 16) * 64];
    ushort* Bl1 = &Bsm[(wave * 16 + 8) * 64];

    // fragment read addresses (ushort offsets), chunk un-swizzle on the read side
    const int l15 = lane & 15, quad = lane >> 4;
    const int xr = l15 & 7;
    const int arow0 = (wm * 32 + l15) * 64, arow1 = arow0 + 16 * 64;
    const int brow0 = (wn * 32 + l15) * 64, brow1 = brow0 + 16 * 64;
    const int c0 = (quad ^ xr) * 8;        // kc=0 chunk
    const int c1 = ((4 + quad) ^ xr) * 8;  // kc=1 chunk

    f32x4 acc00 = {0.f, 0.f, 0.f, 0.f}, acc01 = {0.f, 0.f, 0.f, 0.f};
    f32x4 acc10 = {0.f, 0.f, 0.f, 0.f}, acc11 = {0.f, 0.f, 0.f, 0.f};

    const int P = DD >> 6;  // 8 phases
    for (int p = 0; p < P; ++p) {
        const int ko = p << 6;
        __syncthreads();  // prior phase's ds_reads complete before overwrite
        gload16(Ag0 + ko, Al0);
        gload16(Ag1 + ko, Al1);
        gload16(Bg0 + ko, Bl0);
        gload16(Bg1 + ko, Bl1);
        __syncthreads();  // drains vmcnt(0) -> tiles resident
        bf16x8 fa0 = *(const bf16x8*)&Asm[arow0 + c0];
        bf16x8 fa1 = *(const bf16x8*)&Asm[arow1 + c0];
        bf16x8 fb0 = *(const bf16x8*)&Bsm[brow0 + c0];
        bf16x8 fb1 = *(const bf16x8*)&Bsm[brow1 + c0];
        acc00 = __builtin_amdgcn_mfma_f32_16x16x32_bf16(fa0, fb0, acc00, 0, 0, 0);
        acc01 = __builtin_amdgcn_mfma_f32_16x16x32_bf16(fa0, fb1, acc01, 0, 0, 0);
        acc10 = __builtin_amdgcn_mfma_f32_16x16x32_bf16(fa1, fb0, acc10, 0, 0, 0);
        acc11 = __builtin_amdgcn_mfma_f32_16x16x32_bf16(fa1, fb1, acc11, 0, 0, 0);
        fa0 = *(const bf16x8*)&Asm[arow0 + c1];
        fa1 = *(const bf16x8*)&Asm[arow1 + c1];
        fb0 = *(const bf16x8*)&Bsm[brow0 + c1];
        fb1 = *(const bf16x8*)&Bsm[brow1 + c1];
        acc00 = __builtin_amdgcn_mfma_f32_16x16x32_bf16(fa0, fb0, acc00, 0, 0, 0);
        acc01 = __builtin_amdgcn_mfma_f32_16x16x32_bf16(fa0, fb1, acc01, 0, 0, 0);
        acc10 = __builtin_amdgcn_mfma_f32_16x16x32_bf16(fa1, fb0, acc10, 0, 0, 0);
        acc11 = __builtin_amdgcn_mfma_f32_16x16x32_bf16(fa1, fb1, acc11, 0, 0, 0);
    }
    // epilogue: C/D layout col=l15, row=quad*4+reg
    const int nA = n0 + wn * 32 + l15;
    float bias0 = 0.f, bias1 = 0.f;
    if (hasb) { bias0 = bias[nA]; bias1 = bias[nA + 16]; }
    float* Cf = (float*)Cp;
    ushort* Cb = (ushort*)Cp;
#pragma unroll
    for (int mt = 0; mt < 2; ++mt) {
        f32x4 accN0 = mt ? acc10 : acc00;
        f32x4 accN1 = mt ? acc11 : acc01;
#pragma unroll
        for (int r = 0; r < 4; ++r) {
            int m = m0 + wm * 32 + mt * 16 + quad * 4 + r;
            float v0 = accN0[r] + bias0;
            float v1 = accN1[r] + bias1;
            if (exp2x) { v0 = __expf(2.0f * v0); v1 = __expf(2.0f * v1); }
            size_t i0 = coff + (size_t)m * N + nA;
            if (obf16) { Cb[i0] = f2b(v0); Cb[i0 + 16] = f2b(v1); }
            else { Cf[i0] = v0; Cf[i0 + 16] = v1; }
        }
    }
}

// ---------------- fused align + sparsemax + output (R6-verbatim) ----------------
// Block = (2 t-rows, b). Mask-compacted score loop — only ACTIVE s rows
// (avg ~50%) get the 512-d loop. Sorted compaction via per-wave ballot ranks.
// Thread = (compact index ci = tid&127, d-half dh = tid>>7). Two d-terms share
// one reciprocal: va/d0 + vb/d1 = (va*d1 + vb*d0) * rcp(d0*d1).
__global__ __launch_bounds__(256) void align6(const float* __restrict__ Ewq,
                                              const ushort* __restrict__ Eu,
                                              const int* __restrict__ mask,
                                              const float* __restrict__ v,
                                              const ushort* __restrict__ M2,
                                              const float* __restrict__ Y,
                                              float* __restrict__ align_out,
                                              float* __restrict__ out0) {
    const int tg = blockIdx.x, b = blockIdx.y;
    const int t0 = tg * 2, t1 = t0 + 1;
    const int bt0 = b * TT + t0, bt1 = bt0 + 1;
    const int tid = threadIdx.x;
    const int lane = tid & 63;
    const int wave = tid >> 6;
    __shared__ float4 EL[DD];            // {E0, E1, v, 0} 8 KB
    __shared__ float pa[2][2][SS];       // partial a [dh][t][ci] 8 KB
    __shared__ float zc0[SS], zc1[SS];   // compact scores -> probs 2 KB
    __shared__ float pf0[SS], pf1[SS];   // full-row probs (zero-init) 2 KB
    __shared__ int lst[SS];              // sorted active s list 1 KB
    __shared__ int lstS0[SS], lstS1[SS]; // support lists 2 KB
    __shared__ float4 cmb[2][128];       // PV partial combine 4 KB
    __shared__ float svp[4];
    __shared__ int wcnt[4];
    __shared__ int cnt[2];

    if (tid < 2) cnt[tid] = 0;
    // ---- sorted mask compaction: ballot rank keeps lst ascending in s ----
    const int mk = mask[b * SS + tid];            // tid == s (SS == 256)
    const unsigned long long bal = __ballot(mk != 0);
    const int wr = __popcll(bal & ((1ull << lane) - 1ull));
    if (lane == 0) wcnt[wave] = __popcll(bal);
    // ---- EL preload + sum(v) (independent work before the sync) ----
    const float* E0p = Ewq + (size_t)bt0 * DD;
    const float* E1p = Ewq + (size_t)bt1 * DD;
    float pv = 0.f;
    for (int d = tid; d < DD; d += 256) {
        float vv = v[d];
        EL[d] = make_float4(E0p[d], E1p[d], vv, 0.f);
        pv += vv;
    }
    pf0[tid] = 0.f;
    pf1[tid] = 0.f;
#pragma unroll
    for (int off = 32; off > 0; off >>= 1) pv += __shfl_xor(pv, off, 64);
    if (lane == 0) svp[wave] = pv;
    __syncthreads();
    const float sv = svp[0] + svp[1] + svp[2] + svp[3];
    int base = 0;
    for (int w = 0; w < wave; ++w) base += wcnt[w];
    const int na = wcnt[0] + wcnt[1] + wcnt[2] + wcnt[3];
    if (mk) lst[base + wr] = tid;
    __syncthreads();

    if (na == 0) {  // pathological all-masked row: sparsemax of all-equal = uniform
        const float u = 1.0f / (float)SS;
        align_out[((size_t)t0 * BB + b) * SS + tid] = u;
        align_out[((size_t)t1 * BB + b) * SS + tid] = u;
        const int ch = tid & 127, sg = tid >> 7;
        if (sg == 0) {
            const ushort* M2b = M2 + (size_t)b * SS * DD + ch * 4;
            float4 at = {0.f, 0.f, 0.f, 0.f};
            for (int s = 0; s < SS; ++s) {
                ushort4 m4 = *(const ushort4*)(M2b + (size_t)s * DD);
                at.x += b2f(m4.x); at.y += b2f(m4.y);
                at.z += b2f(m4.z); at.w += b2f(m4.w);
            }
            const float4* Y0 = (const float4*)(Y + (size_t)bt0 * DD);
            const float4* Y1 = (const float4*)(Y + (size_t)bt1 * DD);
            float4 y0 = Y0[ch], y1 = Y1[ch];
            float4 o0 = {at.x * u + y0.x, at.y * u + y0.y, at.z * u + y0.z, at.w * u + y0.w};
            float4 o1 = {at.x * u + y1.x, at.y * u + y1.y, at.z * u + y1.z, at.w * u + y1.w};
            ((float4*)(out0 + ((size_t)t0 * BB + b) * DD))[ch] = o0;
            ((float4*)(out0 + ((size_t)t1 * BB + b) * DD))[ch] = o1;
        }
        return;
    }

    // ---- scores on active rows only; thread owns (ci, d-half) ----
    const int ci0 = tid & 127, dh = tid >> 7;
    const int dbase = dh * 256;
    for (int ci = ci0; ci < na; ci += 128) {
        const int s = lst[ci];
        const ushort* U = Eu + ((size_t)b * SS + s) * DD + dbase;
        float a0 = 0.f, a1 = 0.f;
#pragma unroll 4
        for (int dd = 0; dd < 256; dd += 8) {
            union { uint4 q; unsigned w[4]; } uw;
            uw.q = *(const uint4*)(U + dd);
#pragma unroll
            for (int jj = 0; jj < 4; ++jj) {
                const unsigned wd = uw.w[jj];
                const float ulo = __builtin_bit_cast(float, wd << 16);
                const float uhi = __builtin_bit_cast(float, wd & 0xffff0000u);
                const float4 eA = EL[dbase + dd + jj * 2];
                const float4 eB = EL[dbase + dd + jj * 2 + 1];
                const float d0 = __builtin_fmaf(eA.x, ulo, 1.0f);
                const float d1 = __builtin_fmaf(eB.x, uhi, 1.0f);
                float num = eA.z * d1;
                num = __builtin_fmaf(eB.z, d0, num);
                a0 = __builtin_fmaf(num, __builtin_amdgcn_rcpf(d0 * d1), a0);
                const float e0 = __builtin_fmaf(eA.y, ulo, 1.0f);
                const float e1 = __builtin_fmaf(eB.y, uhi, 1.0f);
                float nu1 = eA.z * e1;
                nu1 = __builtin_fmaf(eB.z, e0, nu1);
                a1 = __builtin_fmaf(nu1, __builtin_amdgcn_rcpf(e0 * e1), a1);
            }
        }
        pa[dh][0][ci] = a0;
        pa[dh][1][ci] = a1;
    }
    __syncthreads();
    for (int ci = tid; ci < na; ci += 256) {
        zc0[ci] = sv - 2.0f * (pa[0][0][ci] + pa[1][0][ci]);
        zc1[ci] = sv - 2.0f * (pa[0][1][ci] + pa[1][1][ci]);
    }
    __syncthreads();

    // ---- sparsemax over compact arrays (length na), waves 0/1 ----
    if (wave < 2) {
        float* zz = wave ? zc1 : zc0;
        float z0 = lane < na ? zz[lane] : -1e9f;
        float z1 = lane + 64 < na ? zz[lane + 64] : -1e9f;
        float z2 = lane + 128 < na ? zz[lane + 128] : -1e9f;
        float z3 = lane + 192 < na ? zz[lane + 192] : -1e9f;
        float mx = fmaxf(fmaxf(z0, z1), fmaxf(z2, z3));
#pragma unroll
        for (int off = 32; off > 0; off >>= 1) mx = fmaxf(mx, __shfl_xor(mx, off, 64));
        z0 -= mx; z1 -= mx; z2 -= mx; z3 -= mx;
        float lo = -1.0f, hi = 0.0f;
        for (int it = 0; it < 20; ++it) {
            float mid = 0.5f * (lo + hi);
            float ssum = fmaxf(z0 - mid, 0.f) + fmaxf(z1 - mid, 0.f) +
                         fmaxf(z2 - mid, 0.f) + fmaxf(z3 - mid, 0.f);
#pragma unroll
            for (int off = 32; off > 0; off >>= 1) ssum += __shfl_xor(ssum, off, 64);
            if (ssum >= 1.0f) lo = mid; else hi = mid;
        }
        float tau = 0.5f * (lo + hi);
        if (lane < na) zz[lane] = fmaxf(z0 - tau, 0.f);
        if (lane + 64 < na) zz[lane + 64] = fmaxf(z1 - tau, 0.f);
        if (lane + 128 < na) zz[lane + 128] = fmaxf(z2 - tau, 0.f);
        if (lane + 192 < na) zz[lane + 192] = fmaxf(z3 - tau, 0.f);
    }
    __syncthreads();

    // ---- scatter probs to full rows + build support lists ----
    for (int ci = tid; ci < na; ci += 256) {
        const int s = lst[ci];
        const float p0 = zc0[ci], p1 = zc1[ci];
        pf0[s] = p0;
        pf1[s] = p1;
        if (p0 > 0.f) lstS0[atomicAdd(&cnt[0], 1)] = s;
        if (p1 > 0.f) lstS1[atomicAdd(&cnt[1], 1)] = s;
    }
    __syncthreads();
    align_out[((size_t)t0 * BB + b) * SS + tid] = pf0[tid];
    align_out[((size_t)t1 * BB + b) * SS + tid] = pf1[tid];
    const int n0c = cnt[0], n1c = cnt[1];

    // ---- PV + Y: thread ch owns d=ch*4..+3 for BOTH t; sg splits list ----
    const int ch = tid & 127, sg = tid >> 7;
    const ushort* M2b = M2 + (size_t)b * SS * DD + ch * 4;
    float4 at0 = {0.f, 0.f, 0.f, 0.f}, at1 = {0.f, 0.f, 0.f, 0.f};
#pragma unroll 4
    for (int j = sg; j < n0c; j += 2) {
        int s = lstS0[j];
        float p = pf0[s];
        ushort4 m4 = *(const ushort4*)(M2b + (size_t)s * DD);
        at0.x = __builtin_fmaf(p, b2f(m4.x), at0.x);
        at0.y = __builtin_fmaf(p, b2f(m4.y), at0.y);
        at0.z = __builtin_fmaf(p, b2f(m4.z), at0.z);
        at0.w = __builtin_fmaf(p, b2f(m4.w), at0.w);
    }
#pragma unroll 4
    for (int j = sg; j < n1c; j += 2) {
        int s = lstS1[j];
        float p = pf1[s];
        ushort4 m4 = *(const ushort4*)(M2b + (size_t)s * DD);
        at1.x = __builtin_fmaf(p, b2f(m4.x), at1.x);
        at1.y = __builtin_fmaf(p, b2f(m4.y), at1.y);
        at1.z = __builtin_fmaf(p, b2f(m4.z), at1.z);
        at1.w = __builtin_fmaf(p, b2f(m4.w), at1.w);
    }
    if (sg == 1) { cmb[0][ch] = at0; cmb[1][ch] = at1; }
    __syncthreads();
    if (sg == 0) {
        float4 p0 = cmb[0][ch], p1 = cmb[1][ch];
        const float4* Y0 = (const float4*)(Y + (size_t)bt0 * DD);
        const float4* Y1 = (const float4*)(Y + (size_t)bt1 * DD);
        float4 y0 = Y0[ch], y1 = Y1[ch];
        float4 o0, o1;
        o0.x = at0.x + p0.x + y0.x; o0.y = at0.y + p0.y + y0.y;
        o0.z = at0.z + p0.z + y0.z; o0.w = at0.w + p0.w + y0.w;
        o1.x = at1.x + p1.x + y1.x; o1.y = at1.y + p1.y + y1.y;
        o1.z = at1.z + p1.z + y1.z; o1.w = at1.w + p1.w + y1.w;
        float4* O0 = (float4*)(out0 + ((size_t)t0 * BB + b) * DD);
        float4* O1 = (float4*)(out0 + ((size_t)t1 * BB + b) * DD);
        O0[ch] = o0;
        O1[ch] = o1;
    }
}

extern "C" void kernel_launch(void* const* d_in, const int* in_sizes, int n_in,
                              void* d_out, int out_size, void* d_ws, size_t ws_size,
                              hipStream_t stream) {
    const float* source = (const float*)d_in[0];       // (B,T,D)
    const float* memory_bank = (const float*)d_in[1];  // (B,S,D)
    const int* memory_mask = (const int*)d_in[2];      // (B,S)
    const float* W_q = (const float*)d_in[3];          // (D,D)
    const float* b_q = (const float*)d_in[4];          // (D,)
    const float* W_c = (const float*)d_in[5];          // (D,D)
    const float* v = (const float*)d_in[6];            // (D,)
    const float* W_out = (const float*)d_in[7];        // (D,2D)
    const float* b_out = (const float*)d_in[8];        // (D,)

    float* out0 = (float*)d_out;                   // attn_h (T,B,D)
    float* out1 = out0 + (size_t)TT * BB * DD;     // align_vectors (T,B,S)

    // workspace (~19.3 MB)
    float* Ewq = (float*)d_ws;                     // (B*T, D) fp32 exp(2wq)  2 MB
    float* Y = Ewq + S_SRC;                        // (B*T, D) fp32 src@Wo2^T+b 2 MB
    ushort* Eu = (ushort*)(Y + S_SRC);             // (B, S, D) bf16 exp(2uh) 4 MB
    ushort* M2 = Eu + S_MB;                        // (B, S, D) bf16 mb@Wo1^T 4 MB
    ushort* src_b = M2 + S_MB;                     // 1 MB
    ushort* mb_b = src_b + S_SRC;                  // 4 MB
    ushort* wqw_b = mb_b + S_MB;                   // 0.5 MB
    ushort* wcw_b = wqw_b + S_WQ;                  // 0.5 MB
    ushort* wo_b = wcw_b + S_WC;                   // 1 MB

    dim3 blk(256);
    // 1. cast bf16 operands
    int ngroups = (S_SRC + S_MB + S_WQ + S_WC + S_WO) / 4;
    cast_all<<<dim3(ngroups / 256), blk, 0, stream>>>(
        source, memory_bank, W_q, W_c, W_out, src_b, mb_b, wqw_b, wcw_b, wo_b);
    // 2. all four GEMMs, one dispatch (1280 blocks of 64x64 tiles, ~5/CU)
    mega_gemm<<<dim3(1280), blk, 0, stream>>>(
        src_b, mb_b, wqw_b, wcw_b, wo_b, b_q, b_out, Ewq, Y, Eu, M2);
    // 3. fused align + sparsemax + output (mask-compacted)
    align6<<<dim3(TT / 2, BB), blk, 0, stream>>>(
        Ewq, Eu, memory_mask, v, M2, Y, out1, out0);
}